// Round 1
// baseline (660.624 us; speedup 1.0000x reference)
//
#include <hip/hip_runtime.h>
#include <math.h>

#define SS 8
#define NBLK 8192
#define DIN 512
#define DOUT 256
#define MT 32            // rows per workgroup (4 graph-blocks)
#define GB 4             // graph blocks per workgroup
#define BK 32            // K chunk
#define KSTEPS (DIN/BK)  // 16
#define CSTR 257         // padded LDS stride (floats)
#define EPSN 1e-12f

typedef __bf16 bf16;
typedef __bf16 bf16x4 __attribute__((ext_vector_type(4)));
typedef __bf16 bf16x8 __attribute__((ext_vector_type(8)));
typedef float  f32x4  __attribute__((ext_vector_type(4)));

// ---------- prep: W_gcn [512 k][256 n] f32  ->  Wt [256 n][512 k] bf16 ----------
__global__ void prep_wt_kernel(const float* __restrict__ W, bf16* __restrict__ Wt) {
    int idx = blockIdx.x * 256 + threadIdx.x;   // 131072 total
    int k = idx >> 8;
    int n = idx & 255;
    Wt[n * DIN + k] = (bf16)W[idx];
}

// ---------- fused GCN + pool + norm + bilinear score ----------
__global__ __launch_bounds__(256, 2) void cola_fused_kernel(
    const float* __restrict__ pos_x, const float* __restrict__ neg_x,
    const int* __restrict__ pos_src, const int* __restrict__ pos_dst,
    const float* __restrict__ pos_w,
    const int* __restrict__ neg_src, const int* __restrict__ neg_dst,
    const float* __restrict__ neg_w,
    const bf16* __restrict__ Wt, const float* __restrict__ b_gcn,
    const float* __restrict__ prelu_a, const float* __restrict__ W_bil,
    const float* __restrict__ b_bil, float* __restrict__ out)
{
    __shared__ float adj[2][GB][SS][SS];     // 4 KB   weighted adjacency per block
    __shared__ float ssq[GB][3];             // pool_pos, anchor, pool_neg sumsq
    __shared__ float score_acc[GB][2];
    __shared__ __align__(16) char regA[20480];   // tiles  U  pool/anchor buffers
    __shared__ float regB[MT * CSTR];            // C dump  U  W_bil chunk (32x257)

    bf16* Apos = (bf16*)regA;                 // 32x32 bf16 = 2 KB
    bf16* Aneg = (bf16*)(regA + 2048);        // 2 KB
    bf16* Btl  = (bf16*)(regA + 4096);        // 256x32 bf16 = 16 KB
    float* pool_pos = (float*)regA;           // [GB][256] (after K-loop)
    float* pool_neg = (float*)(regA + 4096);
    float* anchor_b = (float*)(regA + 8192);

    const int t    = threadIdx.x;
    const int wg   = blockIdx.x;
    const int row0 = wg * MT;
    const int gb0  = wg * GB;
    const int lane = t & 63;
    const int wv   = t >> 6;
    const int q    = lane >> 4;
    const int r15  = lane & 15;

    // ---- zero accumulators + adjacency ----
    if (t < GB * 3) ((float*)ssq)[t] = 0.f;
    if (t < GB * 2) ((float*)score_acc)[t] = 0.f;
    {
        float* a = (float*)adj;
        for (int i = t; i < 2 * GB * 64; i += 256) a[i] = 0.f;
    }
    __syncthreads();

    // ---- build adjacency: edges are block-contiguous, 64/block, 256/wg/branch ----
    {
        int e = wg * 256 + t;                 // global edge index
        int g = t >> 6;                       // local graph-block
        int base = (gb0 + g) * SS;
        int sp = pos_src[e] - base, dp = pos_dst[e] - base;
        atomicAdd(&adj[0][g][dp][sp], pos_w[e]);
        int sn = neg_src[e] - base, dn = neg_dst[e] - base;
        atomicAdd(&adj[1][g][dn][sn], neg_w[e]);
    }
    // (K-loop barriers cover adj visibility before epilogue use)

    // ---- GEMM: C = X @ W_gcn for pos & neg, M=32, N=256, K=512 ----
    f32x4 accp[2][4], accn[2][4];
#pragma unroll
    for (int m = 0; m < 2; m++)
#pragma unroll
        for (int j = 0; j < 4; j++) {
            accp[m][j] = (f32x4){0.f, 0.f, 0.f, 0.f};
            accn[m][j] = (f32x4){0.f, 0.f, 0.f, 0.f};
        }

    const int arow = t >> 3;          // 0..31
    const int akq  = (t & 7) * 4;     // 0..28
    const int bj   = (t & 3) * 8;     // k-subchunk within B row
    const int bn   = t >> 2;          // 0..63

    for (int step = 0; step < KSTEPS; ++step) {
        const int k0 = step * BK;
        // stage A (fp32 -> bf16 in registers)
        {
            const float4 vp = *(const float4*)(pos_x + (size_t)(row0 + arow) * DIN + k0 + akq);
            const float4 vn = *(const float4*)(neg_x + (size_t)(row0 + arow) * DIN + k0 + akq);
            bf16x4 cp, cn;
            cp[0] = (bf16)vp.x; cp[1] = (bf16)vp.y; cp[2] = (bf16)vp.z; cp[3] = (bf16)vp.w;
            cn[0] = (bf16)vn.x; cn[1] = (bf16)vn.y; cn[2] = (bf16)vn.z; cn[3] = (bf16)vn.w;
            *(bf16x4*)(Apos + arow * BK + akq) = cp;
            *(bf16x4*)(Aneg + arow * BK + akq) = cn;
        }
        // stage B (pre-converted bf16, coalesced 16B per lane)
#pragma unroll
        for (int c = 0; c < 4; ++c) {
            int n = c * 64 + bn;
            uint4 v = *(const uint4*)(Wt + (size_t)n * DIN + k0 + bj);
            *(uint4*)(Btl + n * BK + bj) = v;
        }
        __syncthreads();

        bf16x8 ap0 = *(const bf16x8*)(Apos + (r15) * BK + q * 8);
        bf16x8 ap1 = *(const bf16x8*)(Apos + (16 + r15) * BK + q * 8);
        bf16x8 an0 = *(const bf16x8*)(Aneg + (r15) * BK + q * 8);
        bf16x8 an1 = *(const bf16x8*)(Aneg + (16 + r15) * BK + q * 8);
#pragma unroll
        for (int j = 0; j < 4; ++j) {
            bf16x8 b = *(const bf16x8*)(Btl + (wv * 64 + j * 16 + r15) * BK + q * 8);
            accp[0][j] = __builtin_amdgcn_mfma_f32_16x16x32_bf16(ap0, b, accp[0][j], 0, 0, 0);
            accp[1][j] = __builtin_amdgcn_mfma_f32_16x16x32_bf16(ap1, b, accp[1][j], 0, 0, 0);
            accn[0][j] = __builtin_amdgcn_mfma_f32_16x16x32_bf16(an0, b, accn[0][j], 0, 0, 0);
            accn[1][j] = __builtin_amdgcn_mfma_f32_16x16x32_bf16(an1, b, accn[1][j], 0, 0, 0);
        }
        __syncthreads();
    }

    // ---- epilogue ----
    const float pa = *prelu_a;
    const float bg = b_gcn[t];    // this thread's column bias

    // dump pos C to regB[32][257]  (C layout: col=lane&15, row=(lane>>4)*4+reg)
#pragma unroll
    for (int m = 0; m < 2; m++)
#pragma unroll
        for (int j = 0; j < 4; j++) {
            int col = wv * 64 + j * 16 + r15;
            int rbase = m * 16 + q * 4;
#pragma unroll
            for (int r = 0; r < 4; r++)
                regB[(rbase + r) * CSTR + col] = accp[m][j][r];
        }
    __syncthreads();

    // aggregate + pool + anchor for pos (thread t owns column t)
    for (int g = 0; g < GB; ++g) {
        float xw[SS];
#pragma unroll
        for (int s = 0; s < SS; s++) xw[s] = regB[(g * SS + s) * CSTR + t];
        float pool = 0.f, anch = 0.f;
#pragma unroll
        for (int d = 0; d < SS; d++) {
            float a = bg;
#pragma unroll
            for (int s = 0; s < SS; s++) a += adj[0][g][d][s] * xw[s];
            float h = (a >= 0.f) ? a : pa * a;
            if (d < SS - 1) pool += h; else anch = h;
        }
        pool *= (1.f / 7.f);
        pool_pos[g * DOUT + t] = pool;
        anchor_b[g * DOUT + t] = anch;
        float sp = pool * pool, sa = anch * anch;
        for (int off = 32; off; off >>= 1) {
            sp += __shfl_down(sp, off);
            sa += __shfl_down(sa, off);
        }
        if (lane == 0) { atomicAdd(&ssq[g][0], sp); atomicAdd(&ssq[g][1], sa); }
    }
    __syncthreads();

    // dump neg C
#pragma unroll
    for (int m = 0; m < 2; m++)
#pragma unroll
        for (int j = 0; j < 4; j++) {
            int col = wv * 64 + j * 16 + r15;
            int rbase = m * 16 + q * 4;
#pragma unroll
            for (int r = 0; r < 4; r++)
                regB[(rbase + r) * CSTR + col] = accn[m][j][r];
        }
    __syncthreads();

    // aggregate + pool for neg (anchor discarded per reference)
    for (int g = 0; g < GB; ++g) {
        float xw[SS];
#pragma unroll
        for (int s = 0; s < SS; s++) xw[s] = regB[(g * SS + s) * CSTR + t];
        float pool = 0.f;
#pragma unroll
        for (int d = 0; d < SS - 1; d++) {
            float a = bg;
#pragma unroll
            for (int s = 0; s < SS; s++) a += adj[1][g][d][s] * xw[s];
            float h = (a >= 0.f) ? a : pa * a;
            pool += h;
        }
        pool *= (1.f / 7.f);
        pool_neg[g * DOUT + t] = pool;
        float sp = pool * pool;
        for (int off = 32; off; off >>= 1) sp += __shfl_down(sp, off);
        if (lane == 0) atomicAdd(&ssq[g][2], sp);
    }

    // ---- bilinear scores: score = pool · W_bil · anchor (chunked W staging) ----
    float psum[GB], nsum[GB];
#pragma unroll
    for (int g = 0; g < GB; ++g) { psum[g] = 0.f; nsum[g] = 0.f; }
    const int dl = t & 31;      // d within chunk
    const int er = t >> 5;      // e-range 0..7 (32 each)

    for (int kd = 0; kd < 8; ++kd) {
        __syncthreads();        // protect regB before restage
        for (int r = 0; r < 32; ++r)
            regB[r * CSTR + t] = W_bil[(size_t)(kd * 32 + r) * DOUT + t];
        __syncthreads();
        for (int g = 0; g < GB; ++g) {
            float part = 0.f;
#pragma unroll
            for (int i = 0; i < 32; ++i)
                part += regB[dl * CSTR + er * 32 + i] * anchor_b[g * DOUT + er * 32 + i];
            int d = kd * 32 + dl;
            psum[g] += pool_pos[g * DOUT + d] * part;
            nsum[g] += pool_neg[g * DOUT + d] * part;
        }
    }

    for (int g = 0; g < GB; ++g) {
        float p = psum[g], n2 = nsum[g];
        for (int off = 32; off; off >>= 1) {
            p  += __shfl_down(p, off);
            n2 += __shfl_down(n2, off);
        }
        if (lane == 0) { atomicAdd(&score_acc[g][0], p); atomicAdd(&score_acc[g][1], n2); }
    }
    __syncthreads();

    if (t < GB) {
        float np = fmaxf(sqrtf(ssq[t][0]), EPSN);
        float na = fmaxf(sqrtf(ssq[t][1]), EPSN);
        float nn = fmaxf(sqrtf(ssq[t][2]), EPSN);
        float bb = b_bil[0];
        out[gb0 + t]        = score_acc[t][0] / (np * na) + bb;
        out[NBLK + gb0 + t] = score_acc[t][1] / (nn * na) + bb;
    }
}

extern "C" void kernel_launch(void* const* d_in, const int* in_sizes, int n_in,
                              void* d_out, int out_size, void* d_ws, size_t ws_size,
                              hipStream_t stream) {
    const float* pos_x   = (const float*)d_in[0];
    const float* neg_x   = (const float*)d_in[1];
    const int*   pos_src = (const int*)d_in[2];
    const int*   pos_dst = (const int*)d_in[3];
    const float* pos_w   = (const float*)d_in[4];
    const int*   neg_src = (const int*)d_in[5];
    const int*   neg_dst = (const int*)d_in[6];
    const float* neg_w   = (const float*)d_in[7];
    const float* W_gcn   = (const float*)d_in[8];
    const float* b_gcn   = (const float*)d_in[9];
    const float* prelu_a = (const float*)d_in[10];
    const float* W_bil   = (const float*)d_in[11];
    const float* b_bil   = (const float*)d_in[12];
    float* outp = (float*)d_out;

    bf16* Wt = (bf16*)d_ws;   // 256 KB

    prep_wt_kernel<<<DIN * DOUT / 256, 256, 0, stream>>>(W_gcn, Wt);
    cola_fused_kernel<<<(NBLK * SS) / MT, 256, 0, stream>>>(
        pos_x, neg_x, pos_src, pos_dst, pos_w, neg_src, neg_dst, neg_w,
        Wt, b_gcn, prelu_a, W_bil, b_bil, outp);
}

// Round 2
// 495.134 us; speedup vs baseline: 1.3342x; 1.3342x over previous
//
#include <hip/hip_runtime.h>
#include <math.h>

#define SS 8
#define NBLK 8192
#define DIN 512
#define DOUT 256
#define GB 8              // graph blocks per WG
#define MT 64             // rows per WG (= GB*SS)
#define BK 32             // K chunk
#define KSTEPS 16         // DIN/BK
#define VSTR 264          // anchor bf16 LDS stride (16B-aligned, bank-spread)
#define EPSN 1e-12f

typedef __bf16 bf16;
typedef __bf16 bf16x8 __attribute__((ext_vector_type(8)));
typedef float  f32x4  __attribute__((ext_vector_type(4)));

// ---- prep: Wt = W_gcn^T in bf16 [n][k]; W_bil split into bf16 hi+lo ----
__global__ void prep_kernel(const float* __restrict__ W_gcn,
                            const float* __restrict__ W_bil,
                            bf16* __restrict__ Wt,
                            bf16* __restrict__ Wh,
                            bf16* __restrict__ Wl) {
    int idx = blockIdx.x * 256 + threadIdx.x;   // 196608 total
    if (idx < DIN * DOUT) {
        int k = idx >> 8, n = idx & 255;
        Wt[n * DIN + k] = (bf16)W_gcn[idx];
    } else {
        int j = idx - DIN * DOUT;               // < 65536
        float wv = W_bil[j];
        bf16 h = (bf16)wv;
        Wh[j] = h;
        Wl[j] = (bf16)(wv - (float)h);
    }
}

// ---- one 64x256x512 GEMM pass (X @ W_gcn), software-pipelined ----
__device__ __forceinline__ void gemm_pass(const float* __restrict__ x,
    const bf16* __restrict__ Wt, bf16* __restrict__ As, bf16* __restrict__ Bs,
    int wg, int t, int w, int q, int r15, f32x4 acc[4][4])
{
#pragma unroll
    for (int mi = 0; mi < 4; ++mi)
#pragma unroll
        for (int ni = 0; ni < 4; ++ni) acc[mi][ni] = (f32x4){0.f, 0.f, 0.f, 0.f};

    const int arow = t >> 2;            // 0..63
    const int akc  = (t & 3) * 8;       // 0,8,16,24
    const float* ap = x + (size_t)(wg * MT + arow) * DIN + akc;
    const bf16*  bp = Wt + (size_t)t * DIN;     // thread t owns B row t
    const int trot = (t >> 1) & 3;      // B write slot rotation (bank spread)

    // preload step 0
    float4 a0 = *(const float4*)(ap);
    float4 a1 = *(const float4*)(ap + 4);
    bf16x8 bv0 = *(const bf16x8*)(bp + 0);
    bf16x8 bv1 = *(const bf16x8*)(bp + 8);
    bf16x8 bv2 = *(const bf16x8*)(bp + 16);
    bf16x8 bv3 = *(const bf16x8*)(bp + 24);

    bf16* aw = As + arow * BK + akc;
    bf16* bw = Bs + t * BK;

    for (int s = 0; s < KSTEPS; ++s) {
        bf16x8 av;
        av[0] = (bf16)a0.x; av[1] = (bf16)a0.y; av[2] = (bf16)a0.z; av[3] = (bf16)a0.w;
        av[4] = (bf16)a1.x; av[5] = (bf16)a1.y; av[6] = (bf16)a1.z; av[7] = (bf16)a1.w;
        *(bf16x8*)aw = av;
        // B chunks rotated: chunk j -> slot (j+trot)&3
        *(bf16x8*)(bw + (((0 + trot) & 3) << 3)) = bv0;
        *(bf16x8*)(bw + (((1 + trot) & 3) << 3)) = bv1;
        *(bf16x8*)(bw + (((2 + trot) & 3) << 3)) = bv2;
        *(bf16x8*)(bw + (((3 + trot) & 3) << 3)) = bv3;
        __syncthreads();

        if (s < KSTEPS - 1) {           // prefetch next step (drains at tail barrier)
            a0 = *(const float4*)(ap + (s + 1) * BK);
            a1 = *(const float4*)(ap + (s + 1) * BK + 4);
            bv0 = *(const bf16x8*)(bp + (s + 1) * BK + 0);
            bv1 = *(const bf16x8*)(bp + (s + 1) * BK + 8);
            bv2 = *(const bf16x8*)(bp + (s + 1) * BK + 16);
            bv3 = *(const bf16x8*)(bp + (s + 1) * BK + 24);
        }

        bf16x8 af[4], bfv[4];
#pragma unroll
        for (int mi = 0; mi < 4; ++mi)
            af[mi] = *(const bf16x8*)(As + (mi * 16 + r15) * BK + q * 8);
#pragma unroll
        for (int ni = 0; ni < 4; ++ni) {
            int n = w * 64 + ni * 16 + r15;
            int slot = (q + ((n >> 1) & 3)) & 3;
            bfv[ni] = *(const bf16x8*)(Bs + n * BK + slot * 8);
        }
#pragma unroll
        for (int mi = 0; mi < 4; ++mi)
#pragma unroll
            for (int ni = 0; ni < 4; ++ni)
                acc[mi][ni] = __builtin_amdgcn_mfma_f32_16x16x32_bf16(
                    af[mi], bfv[ni], acc[mi][ni], 0, 0, 0);
        __syncthreads();
    }
}

__global__ __launch_bounds__(256, 3) void cola_fused2(
    const float* __restrict__ pos_x, const float* __restrict__ neg_x,
    const int* __restrict__ pos_src, const int* __restrict__ pos_dst,
    const float* __restrict__ pos_w,
    const int* __restrict__ neg_src, const int* __restrict__ neg_dst,
    const float* __restrict__ neg_w,
    const bf16* __restrict__ Wt, const bf16* __restrict__ Wh,
    const bf16* __restrict__ Wl,
    const float* __restrict__ b_gcn, const float* __restrict__ prelu_a,
    const float* __restrict__ b_bil, float* __restrict__ out)
{
    __shared__ bf16  As[MT * BK];            // 4 KB
    __shared__ bf16  Bs[DOUT * BK];          // 16 KB
    __shared__ float pool_pos[GB * DOUT];    // 8 KB
    __shared__ float v_lds[GB * DOUT];       // 8 KB
    __shared__ bf16  ahs[GB * VSTR];         // 4.125 KB  anchor hi
    __shared__ bf16  als[GB * VSTR];         // 4.125 KB  anchor lo
    __shared__ float adjP[GB][SS][SS];       // 2 KB
    __shared__ float adjN[GB][SS][SS];       // 2 KB
    __shared__ float red[5 * GB];            // ssqP|ssqA|ssqN|scoreP|scoreN

    const int t   = threadIdx.x;
    const int wg  = blockIdx.x;
    const int w   = t >> 6;
    const int lane = t & 63;
    const int q   = lane >> 4;
    const int r15 = lane & 15;

    // ---- zero adjacency + reductions ----
    for (int i = t; i < GB * 64; i += 256) { ((float*)adjP)[i] = 0.f; ((float*)adjN)[i] = 0.f; }
    if (t < 5 * GB) red[t] = 0.f;
    __syncthreads();

    // ---- build weighted adjacency (edges are block-contiguous, 64/block) ----
    {
        int2   sp2 = ((const int2*)pos_src)[wg * 256 + t];
        int2   dp2 = ((const int2*)pos_dst)[wg * 256 + t];
        float2 wp2 = ((const float2*)pos_w)[wg * 256 + t];
        int2   sn2 = ((const int2*)neg_src)[wg * 256 + t];
        int2   dn2 = ((const int2*)neg_dst)[wg * 256 + t];
        float2 wn2 = ((const float2*)neg_w)[wg * 256 + t];
        int gl = t >> 5;                        // both edges in same block
        int base = (wg * GB + gl) * SS;
        atomicAdd(&adjP[gl][dp2.x - base][sp2.x - base], wp2.x);
        atomicAdd(&adjP[gl][dp2.y - base][sp2.y - base], wp2.y);
        atomicAdd(&adjN[gl][dn2.x - base][sn2.x - base], wn2.x);
        atomicAdd(&adjN[gl][dn2.y - base][sn2.y - base], wn2.y);
    }
    // visibility of adj covered by the K-loop barriers before first use

    const float pa = *prelu_a;
    float bgc[4];
#pragma unroll
    for (int ni = 0; ni < 4; ++ni) bgc[ni] = b_gcn[w * 64 + ni * 16 + r15];

    f32x4 acc[4][4];

    // ================= POS branch =================
    gemm_pass(pos_x, Wt, As, Bs, wg, t, w, q, r15, acc);

#pragma unroll
    for (int mi = 0; mi < 4; ++mi) {
        const int gl = mi * 2 + (q >> 1);
        float rows[4][8];
#pragma unroll
        for (int ni = 0; ni < 4; ++ni)
#pragma unroll
            for (int r = 0; r < 4; ++r) {
                float own = acc[mi][ni][r];
                float oth = __shfl_xor(own, 16);
                if ((q & 1) == 0) { rows[ni][r] = own; rows[ni][4 + r] = oth; }
                else              { rows[ni][r] = oth; rows[ni][4 + r] = own; }
            }
        float pool[4] = {0.f, 0.f, 0.f, 0.f};
        float anch[4] = {0.f, 0.f, 0.f, 0.f};
#pragma unroll
        for (int d = 0; d < 8; ++d) {
            const float* ar = &adjP[gl][d][0];
            float c0 = ar[0], c1 = ar[1], c2 = ar[2], c3 = ar[3];
            float c4 = ar[4], c5 = ar[5], c6 = ar[6], c7 = ar[7];
#pragma unroll
            for (int ni = 0; ni < 4; ++ni) {
                float a = bgc[ni]
                    + c0 * rows[ni][0] + c1 * rows[ni][1] + c2 * rows[ni][2] + c3 * rows[ni][3]
                    + c4 * rows[ni][4] + c5 * rows[ni][5] + c6 * rows[ni][6] + c7 * rows[ni][7];
                float h = (a >= 0.f) ? a : pa * a;
                if (d < 7) pool[ni] += h; else anch[ni] = h;
            }
        }
        float part = 0.f;
#pragma unroll
        for (int ni = 0; ni < 4; ++ni) {
            int c = w * 64 + ni * 16 + r15;
            float pl = pool[ni] * (1.f / 7.f);
            if ((q & 1) == 0) {
                pool_pos[gl * DOUT + c] = pl;
                part += pl * pl;
            } else {
                bf16 hh = (bf16)anch[ni];
                ahs[gl * VSTR + c] = hh;
                als[gl * VSTR + c] = (bf16)(anch[ni] - (float)hh);
                part += anch[ni] * anch[ni];
            }
        }
        part += __shfl_xor(part, 8);
        part += __shfl_xor(part, 4);
        part += __shfl_xor(part, 2);
        part += __shfl_xor(part, 1);
        if (r15 == 0) atomicAdd((q & 1) ? &red[GB + gl] : &red[gl], part);
    }
    __syncthreads();

    // ================= v = W_bil . anchor  (3-term bf16 split MFMA) =================
    {
        f32x4 accv[4];
#pragma unroll
        for (int ni = 0; ni < 4; ++ni) accv[ni] = (f32x4){0.f, 0.f, 0.f, 0.f};
        const int ga = (r15 & 7) * VSTR;        // rows 8..15 duplicate 0..7 (discarded)
#pragma unroll
        for (int ks = 0; ks < 8; ++ks) {
            bf16x8 ah_f = *(const bf16x8*)(ahs + ga + ks * 32 + q * 8);
            bf16x8 al_f = *(const bf16x8*)(als + ga + ks * 32 + q * 8);
#pragma unroll
            for (int ni = 0; ni < 4; ++ni) {
                int d = w * 64 + ni * 16 + r15;
                bf16x8 bh = *(const bf16x8*)(Wh + (size_t)d * DOUT + ks * 32 + q * 8);
                bf16x8 bl = *(const bf16x8*)(Wl + (size_t)d * DOUT + ks * 32 + q * 8);
                accv[ni] = __builtin_amdgcn_mfma_f32_16x16x32_bf16(ah_f, bh, accv[ni], 0, 0, 0);
                accv[ni] = __builtin_amdgcn_mfma_f32_16x16x32_bf16(al_f, bh, accv[ni], 0, 0, 0);
                accv[ni] = __builtin_amdgcn_mfma_f32_16x16x32_bf16(ah_f, bl, accv[ni], 0, 0, 0);
            }
        }
        float sp[4] = {0.f, 0.f, 0.f, 0.f};
        if (q < 2) {
#pragma unroll
            for (int ni = 0; ni < 4; ++ni) {
                int c = w * 64 + ni * 16 + r15;
#pragma unroll
                for (int r = 0; r < 4; ++r) {
                    int g = q * 4 + r;
                    v_lds[g * DOUT + c] = accv[ni][r];
                    sp[r] += accv[ni][r] * pool_pos[g * DOUT + c];
                }
            }
        }
#pragma unroll
        for (int r = 0; r < 4; ++r) {
            sp[r] += __shfl_xor(sp[r], 8);
            sp[r] += __shfl_xor(sp[r], 4);
            sp[r] += __shfl_xor(sp[r], 2);
            sp[r] += __shfl_xor(sp[r], 1);
        }
        if (q < 2 && r15 == 0) {
#pragma unroll
            for (int r = 0; r < 4; ++r) atomicAdd(&red[3 * GB + q * 4 + r], sp[r]);
        }
    }
    __syncthreads();

    // ================= NEG branch =================
    gemm_pass(neg_x, Wt, As, Bs, wg, t, w, q, r15, acc);

#pragma unroll
    for (int mi = 0; mi < 4; ++mi) {
        const int gl = mi * 2 + (q >> 1);
        float rows[4][8];
#pragma unroll
        for (int ni = 0; ni < 4; ++ni)
#pragma unroll
            for (int r = 0; r < 4; ++r) {
                float own = acc[mi][ni][r];
                float oth = __shfl_xor(own, 16);
                if ((q & 1) == 0) { rows[ni][r] = own; rows[ni][4 + r] = oth; }
                else              { rows[ni][r] = oth; rows[ni][4 + r] = own; }
            }
        float pool[4] = {0.f, 0.f, 0.f, 0.f};
#pragma unroll
        for (int d = 0; d < 7; ++d) {
            const float* ar = &adjN[gl][d][0];
            float c0 = ar[0], c1 = ar[1], c2 = ar[2], c3 = ar[3];
            float c4 = ar[4], c5 = ar[5], c6 = ar[6], c7 = ar[7];
#pragma unroll
            for (int ni = 0; ni < 4; ++ni) {
                float a = bgc[ni]
                    + c0 * rows[ni][0] + c1 * rows[ni][1] + c2 * rows[ni][2] + c3 * rows[ni][3]
                    + c4 * rows[ni][4] + c5 * rows[ni][5] + c6 * rows[ni][6] + c7 * rows[ni][7];
                float h = (a >= 0.f) ? a : pa * a;
                pool[ni] += h;
            }
        }
        float part = 0.f;
#pragma unroll
        for (int ni = 0; ni < 4; ++ni) {
            int c = w * 64 + ni * 16 + r15;
            float pl = pool[ni] * (1.f / 7.f);
            part += ((q & 1) == 0) ? pl * v_lds[gl * DOUT + c] : pl * pl;
        }
        part += __shfl_xor(part, 8);
        part += __shfl_xor(part, 4);
        part += __shfl_xor(part, 2);
        part += __shfl_xor(part, 1);
        if (r15 == 0) atomicAdd((q & 1) ? &red[2 * GB + gl] : &red[4 * GB + gl], part);
    }
    __syncthreads();

    // ================= finalize =================
    if (t < GB) {
        float np = fmaxf(sqrtf(red[t]), EPSN);
        float na = fmaxf(sqrtf(red[GB + t]), EPSN);
        float nn = fmaxf(sqrtf(red[2 * GB + t]), EPSN);
        float bb = b_bil[0];
        out[wg * GB + t]        = red[3 * GB + t] / (np * na) + bb;
        out[NBLK + wg * GB + t] = red[4 * GB + t] / (nn * na) + bb;
    }
}

extern "C" void kernel_launch(void* const* d_in, const int* in_sizes, int n_in,
                              void* d_out, int out_size, void* d_ws, size_t ws_size,
                              hipStream_t stream) {
    const float* pos_x   = (const float*)d_in[0];
    const float* neg_x   = (const float*)d_in[1];
    const int*   pos_src = (const int*)d_in[2];
    const int*   pos_dst = (const int*)d_in[3];
    const float* pos_w   = (const float*)d_in[4];
    const int*   neg_src = (const int*)d_in[5];
    const int*   neg_dst = (const int*)d_in[6];
    const float* neg_w   = (const float*)d_in[7];
    const float* W_gcn   = (const float*)d_in[8];
    const float* b_gcn   = (const float*)d_in[9];
    const float* prelu_a = (const float*)d_in[10];
    const float* W_bil   = (const float*)d_in[11];
    const float* b_bil   = (const float*)d_in[12];
    float* outp = (float*)d_out;

    bf16* Wt = (bf16*)d_ws;                 // 256 KB
    bf16* Wh = Wt + DIN * DOUT;             // 128 KB
    bf16* Wl = Wh + DOUT * DOUT;            // 128 KB

    prep_kernel<<<(DIN * DOUT + DOUT * DOUT) / 256, 256, 0, stream>>>(W_gcn, W_bil, Wt, Wh, Wl);
    cola_fused2<<<NBLK / GB, 256, 0, stream>>>(
        pos_x, neg_x, pos_src, pos_dst, pos_w, neg_src, neg_dst, neg_w,
        Wt, Wh, Wl, b_gcn, prelu_a, b_bil, outp);
}

// Round 3
// 367.017 us; speedup vs baseline: 1.8000x; 1.3491x over previous
//
#include <hip/hip_runtime.h>
#include <math.h>

#define SS 8
#define NBLK 8192
#define DIN 512
#define DOUT 256
#define GB 8              // graph blocks per WG
#define MT 64             // rows per WG (= GB*SS)
#define BK 32             // K chunk
#define KSTEPS 16         // DIN/BK
#define VSTR 264          // anchor bf16 LDS stride
#define EPSN 1e-12f

typedef __bf16 bf16;
typedef __bf16 bf16x8 __attribute__((ext_vector_type(8)));
typedef float  f32x4  __attribute__((ext_vector_type(4)));

// ---- prep: Wt = W_gcn^T in bf16 [n][k]; W_bil split into bf16 hi+lo ----
__global__ void prep_kernel(const float* __restrict__ W_gcn,
                            const float* __restrict__ W_bil,
                            bf16* __restrict__ Wt,
                            bf16* __restrict__ Wh,
                            bf16* __restrict__ Wl) {
    int idx = blockIdx.x * 256 + threadIdx.x;   // 196608 total
    if (idx < DIN * DOUT) {
        int k = idx >> 8, n = idx & 255;
        Wt[n * DIN + k] = (bf16)W_gcn[idx];
    } else {
        int j = idx - DIN * DOUT;               // < 65536
        float wv = W_bil[j];
        bf16 h = (bf16)wv;
        Wh[j] = h;
        Wl[j] = (bf16)(wv - (float)h);
    }
}

__global__ __launch_bounds__(256, 2) void cola_fused3(
    const float* __restrict__ pos_x, const float* __restrict__ neg_x,
    const int* __restrict__ pos_src, const int* __restrict__ pos_dst,
    const float* __restrict__ pos_w,
    const int* __restrict__ neg_src, const int* __restrict__ neg_dst,
    const float* __restrict__ neg_w,
    const bf16* __restrict__ Wt, const bf16* __restrict__ Wh,
    const bf16* __restrict__ Wl,
    const float* __restrict__ b_gcn, const float* __restrict__ prelu_a,
    const float* __restrict__ b_bil, float* __restrict__ out)
{
    __shared__ bf16  AsP[MT * BK];           // 4 KB
    __shared__ bf16  AsN[MT * BK];           // 4 KB
    __shared__ bf16  Bs[DOUT * BK];          // 16 KB
    __shared__ float pool_pos[GB * DOUT];    // 8 KB
    __shared__ float v_lds[GB * DOUT];       // 8 KB
    __shared__ bf16  ahs[GB * VSTR];         // 4.125 KB
    __shared__ bf16  als[GB * VSTR];         // 4.125 KB
    __shared__ float adjP[GB][SS][SS];       // 2 KB
    __shared__ float adjN[GB][SS][SS];       // 2 KB
    __shared__ float red[5 * GB];            // ssqP|ssqA|ssqN|scoreP|scoreN

    const int t    = threadIdx.x;
    const int wg   = blockIdx.x;
    const int w    = t >> 6;
    const int lane = t & 63;
    const int q    = lane >> 4;
    const int r15  = lane & 15;

    // ---- zero adjacency + reductions ----
    for (int i = t; i < GB * 64; i += 256) { ((float*)adjP)[i] = 0.f; ((float*)adjN)[i] = 0.f; }
    if (t < 5 * GB) red[t] = 0.f;
    __syncthreads();

    // ---- build weighted adjacency (edges block-contiguous, 64/block) ----
    {
        int2   sp2 = ((const int2*)pos_src)[wg * 256 + t];
        int2   dp2 = ((const int2*)pos_dst)[wg * 256 + t];
        float2 wp2 = ((const float2*)pos_w)[wg * 256 + t];
        int2   sn2 = ((const int2*)neg_src)[wg * 256 + t];
        int2   dn2 = ((const int2*)neg_dst)[wg * 256 + t];
        float2 wn2 = ((const float2*)neg_w)[wg * 256 + t];
        int gl = t >> 5;
        int base = (wg * GB + gl) * SS;
        atomicAdd(&adjP[gl][dp2.x - base][sp2.x - base], wp2.x);
        atomicAdd(&adjP[gl][dp2.y - base][sp2.y - base], wp2.y);
        atomicAdd(&adjN[gl][dn2.x - base][sn2.x - base], wn2.x);
        atomicAdd(&adjN[gl][dn2.y - base][sn2.y - base], wn2.y);
    }
    // adj visibility covered by K-loop barriers before epilogue use

    // ================= combined GEMM: both branches, one K-loop =================
    f32x4 accp[4][4], accn[4][4];
#pragma unroll
    for (int mi = 0; mi < 4; ++mi)
#pragma unroll
        for (int ni = 0; ni < 4; ++ni) {
            accp[mi][ni] = (f32x4){0.f, 0.f, 0.f, 0.f};
            accn[mi][ni] = (f32x4){0.f, 0.f, 0.f, 0.f};
        }

    const int arow = t >> 2;            // 0..63
    const int akc  = (t & 3) * 8;       // 0,8,16,24
    const float* app = pos_x + (size_t)(wg * MT + arow) * DIN + akc;
    const float* anp = neg_x + (size_t)(wg * MT + arow) * DIN + akc;
    const bf16*  bp  = Wt + (size_t)t * DIN;
    const int trot = (t >> 1) & 3;      // B slot rotation (bank spread)

    // preload step 0
    float4 pa0 = *(const float4*)(app);
    float4 pa1 = *(const float4*)(app + 4);
    float4 na0 = *(const float4*)(anp);
    float4 na1 = *(const float4*)(anp + 4);
    bf16x8 bv0 = *(const bf16x8*)(bp + 0);
    bf16x8 bv1 = *(const bf16x8*)(bp + 8);
    bf16x8 bv2 = *(const bf16x8*)(bp + 16);
    bf16x8 bv3 = *(const bf16x8*)(bp + 24);

    bf16* awP = AsP + arow * BK + akc;
    bf16* awN = AsN + arow * BK + akc;
    bf16* bw  = Bs + t * BK;

    for (int s = 0; s < KSTEPS; ++s) {
        bf16x8 av;
        av[0] = (bf16)pa0.x; av[1] = (bf16)pa0.y; av[2] = (bf16)pa0.z; av[3] = (bf16)pa0.w;
        av[4] = (bf16)pa1.x; av[5] = (bf16)pa1.y; av[6] = (bf16)pa1.z; av[7] = (bf16)pa1.w;
        *(bf16x8*)awP = av;
        av[0] = (bf16)na0.x; av[1] = (bf16)na0.y; av[2] = (bf16)na0.z; av[3] = (bf16)na0.w;
        av[4] = (bf16)na1.x; av[5] = (bf16)na1.y; av[6] = (bf16)na1.z; av[7] = (bf16)na1.w;
        *(bf16x8*)awN = av;
        *(bf16x8*)(bw + (((0 + trot) & 3) << 3)) = bv0;
        *(bf16x8*)(bw + (((1 + trot) & 3) << 3)) = bv1;
        *(bf16x8*)(bw + (((2 + trot) & 3) << 3)) = bv2;
        *(bf16x8*)(bw + (((3 + trot) & 3) << 3)) = bv3;
        __syncthreads();

        if (s < KSTEPS - 1) {           // prefetch next step
            pa0 = *(const float4*)(app + (s + 1) * BK);
            pa1 = *(const float4*)(app + (s + 1) * BK + 4);
            na0 = *(const float4*)(anp + (s + 1) * BK);
            na1 = *(const float4*)(anp + (s + 1) * BK + 4);
            bv0 = *(const bf16x8*)(bp + (s + 1) * BK + 0);
            bv1 = *(const bf16x8*)(bp + (s + 1) * BK + 8);
            bv2 = *(const bf16x8*)(bp + (s + 1) * BK + 16);
            bv3 = *(const bf16x8*)(bp + (s + 1) * BK + 24);
        }

        bf16x8 afp[4], afn[4], bfv[4];
#pragma unroll
        for (int mi = 0; mi < 4; ++mi) {
            afp[mi] = *(const bf16x8*)(AsP + (mi * 16 + r15) * BK + q * 8);
            afn[mi] = *(const bf16x8*)(AsN + (mi * 16 + r15) * BK + q * 8);
        }
#pragma unroll
        for (int ni = 0; ni < 4; ++ni) {
            int n = w * 64 + ni * 16 + r15;
            int slot = (q + ((n >> 1) & 3)) & 3;
            bfv[ni] = *(const bf16x8*)(Bs + n * BK + slot * 8);
        }
#pragma unroll
        for (int mi = 0; mi < 4; ++mi)
#pragma unroll
            for (int ni = 0; ni < 4; ++ni) {
                accp[mi][ni] = __builtin_amdgcn_mfma_f32_16x16x32_bf16(
                    afp[mi], bfv[ni], accp[mi][ni], 0, 0, 0);
                accn[mi][ni] = __builtin_amdgcn_mfma_f32_16x16x32_bf16(
                    afn[mi], bfv[ni], accn[mi][ni], 0, 0, 0);
            }
        __syncthreads();
    }

    const float pa = *prelu_a;

    // ================= POS epilogue (per-ni streaming, low reg pressure) ======
#pragma unroll
    for (int mi = 0; mi < 4; ++mi) {
        const int gl = mi * 2 + (q >> 1);
        float part = 0.f;
#pragma unroll
        for (int ni = 0; ni < 4; ++ni) {
            float r0, r1, r2, r3, r4, r5, r6, r7;
#pragma unroll
            for (int r = 0; r < 4; ++r) {
                float own = accp[mi][ni][r];
                float oth = __shfl_xor(own, 16);
                float lo = ((q & 1) == 0) ? own : oth;
                float hi = ((q & 1) == 0) ? oth : own;
                if (r == 0) { r0 = lo; r4 = hi; }
                else if (r == 1) { r1 = lo; r5 = hi; }
                else if (r == 2) { r2 = lo; r6 = hi; }
                else            { r3 = lo; r7 = hi; }
            }
            int c = w * 64 + ni * 16 + r15;
            float bg = b_gcn[c];
            float pool = 0.f, anch = 0.f;
#pragma unroll
            for (int d = 0; d < 8; ++d) {
                const float* ar = &adjP[gl][d][0];
                float a = bg + ar[0]*r0 + ar[1]*r1 + ar[2]*r2 + ar[3]*r3
                             + ar[4]*r4 + ar[5]*r5 + ar[6]*r6 + ar[7]*r7;
                float h = (a >= 0.f) ? a : pa * a;
                if (d < 7) pool += h; else anch = h;
            }
            float pl = pool * (1.f / 7.f);
            if ((q & 1) == 0) {
                pool_pos[gl * DOUT + c] = pl;
                part += pl * pl;
            } else {
                bf16 hh = (bf16)anch;
                ahs[gl * VSTR + c] = hh;
                als[gl * VSTR + c] = (bf16)(anch - (float)hh);
                part += anch * anch;
            }
        }
        part += __shfl_xor(part, 8);
        part += __shfl_xor(part, 4);
        part += __shfl_xor(part, 2);
        part += __shfl_xor(part, 1);
        if (r15 == 0) atomicAdd((q & 1) ? &red[GB + gl] : &red[gl], part);
    }
    __syncthreads();

    // ================= v = W_bil . anchor  (3-term bf16 split MFMA) ===========
    {
        f32x4 accv[4];
#pragma unroll
        for (int ni = 0; ni < 4; ++ni) accv[ni] = (f32x4){0.f, 0.f, 0.f, 0.f};
        const int ga = (r15 & 7) * VSTR;        // rows 8..15 duplicate 0..7
#pragma unroll
        for (int ks = 0; ks < 8; ++ks) {
            bf16x8 ah_f = *(const bf16x8*)(ahs + ga + ks * 32 + q * 8);
            bf16x8 al_f = *(const bf16x8*)(als + ga + ks * 32 + q * 8);
#pragma unroll
            for (int ni = 0; ni < 4; ++ni) {
                int d = w * 64 + ni * 16 + r15;
                bf16x8 bh = *(const bf16x8*)(Wh + (size_t)d * DOUT + ks * 32 + q * 8);
                bf16x8 bl = *(const bf16x8*)(Wl + (size_t)d * DOUT + ks * 32 + q * 8);
                accv[ni] = __builtin_amdgcn_mfma_f32_16x16x32_bf16(ah_f, bh, accv[ni], 0, 0, 0);
                accv[ni] = __builtin_amdgcn_mfma_f32_16x16x32_bf16(al_f, bh, accv[ni], 0, 0, 0);
                accv[ni] = __builtin_amdgcn_mfma_f32_16x16x32_bf16(ah_f, bl, accv[ni], 0, 0, 0);
            }
        }
        float sp[4] = {0.f, 0.f, 0.f, 0.f};
        if (q < 2) {
#pragma unroll
            for (int ni = 0; ni < 4; ++ni) {
                int c = w * 64 + ni * 16 + r15;
#pragma unroll
                for (int r = 0; r < 4; ++r) {
                    int g = q * 4 + r;
                    v_lds[g * DOUT + c] = accv[ni][r];
                    sp[r] += accv[ni][r] * pool_pos[g * DOUT + c];
                }
            }
        }
#pragma unroll
        for (int r = 0; r < 4; ++r) {
            sp[r] += __shfl_xor(sp[r], 8);
            sp[r] += __shfl_xor(sp[r], 4);
            sp[r] += __shfl_xor(sp[r], 2);
            sp[r] += __shfl_xor(sp[r], 1);
        }
        if (q < 2 && r15 == 0) {
#pragma unroll
            for (int r = 0; r < 4; ++r) atomicAdd(&red[3 * GB + q * 4 + r], sp[r]);
        }
    }
    __syncthreads();

    // ================= NEG epilogue ===========================================
#pragma unroll
    for (int mi = 0; mi < 4; ++mi) {
        const int gl = mi * 2 + (q >> 1);
        float part = 0.f;
#pragma unroll
        for (int ni = 0; ni < 4; ++ni) {
            float r0, r1, r2, r3, r4, r5, r6, r7;
#pragma unroll
            for (int r = 0; r < 4; ++r) {
                float own = accn[mi][ni][r];
                float oth = __shfl_xor(own, 16);
                float lo = ((q & 1) == 0) ? own : oth;
                float hi = ((q & 1) == 0) ? oth : own;
                if (r == 0) { r0 = lo; r4 = hi; }
                else if (r == 1) { r1 = lo; r5 = hi; }
                else if (r == 2) { r2 = lo; r6 = hi; }
                else            { r3 = lo; r7 = hi; }
            }
            int c = w * 64 + ni * 16 + r15;
            float bg = b_gcn[c];
            float pool = 0.f;
#pragma unroll
            for (int d = 0; d < 7; ++d) {
                const float* ar = &adjN[gl][d][0];
                float a = bg + ar[0]*r0 + ar[1]*r1 + ar[2]*r2 + ar[3]*r3
                             + ar[4]*r4 + ar[5]*r5 + ar[6]*r6 + ar[7]*r7;
                float h = (a >= 0.f) ? a : pa * a;
                pool += h;
            }
            float pl = pool * (1.f / 7.f);
            part += ((q & 1) == 0) ? pl * v_lds[gl * DOUT + c] : pl * pl;
        }
        part += __shfl_xor(part, 8);
        part += __shfl_xor(part, 4);
        part += __shfl_xor(part, 2);
        part += __shfl_xor(part, 1);
        if (r15 == 0) atomicAdd((q & 1) ? &red[2 * GB + gl] : &red[4 * GB + gl], part);
    }
    __syncthreads();

    // ================= finalize ===============================================
    if (t < GB) {
        float np = fmaxf(sqrtf(red[t]), EPSN);
        float na = fmaxf(sqrtf(red[GB + t]), EPSN);
        float nn = fmaxf(sqrtf(red[2 * GB + t]), EPSN);
        float bb = b_bil[0];
        out[wg * GB + t]        = red[3 * GB + t] / (np * na) + bb;
        out[NBLK + wg * GB + t] = red[4 * GB + t] / (nn * na) + bb;
    }
}

extern "C" void kernel_launch(void* const* d_in, const int* in_sizes, int n_in,
                              void* d_out, int out_size, void* d_ws, size_t ws_size,
                              hipStream_t stream) {
    const float* pos_x   = (const float*)d_in[0];
    const float* neg_x   = (const float*)d_in[1];
    const int*   pos_src = (const int*)d_in[2];
    const int*   pos_dst = (const int*)d_in[3];
    const float* pos_w   = (const float*)d_in[4];
    const int*   neg_src = (const int*)d_in[5];
    const int*   neg_dst = (const int*)d_in[6];
    const float* neg_w   = (const float*)d_in[7];
    const float* W_gcn   = (const float*)d_in[8];
    const float* b_gcn   = (const float*)d_in[9];
    const float* prelu_a = (const float*)d_in[10];
    const float* W_bil   = (const float*)d_in[11];
    const float* b_bil   = (const float*)d_in[12];
    float* outp = (float*)d_out;

    bf16* Wt = (bf16*)d_ws;                 // 256 KB
    bf16* Wh = Wt + DIN * DOUT;             // 128 KB
    bf16* Wl = Wh + DOUT * DOUT;            // 128 KB

    prep_kernel<<<(DIN * DOUT + DOUT * DOUT) / 256, 256, 0, stream>>>(W_gcn, W_bil, Wt, Wh, Wl);
    cola_fused3<<<NBLK / GB, 256, 0, stream>>>(
        pos_x, neg_x, pos_src, pos_dst, pos_w, neg_src, neg_dst, neg_w,
        Wt, Wh, Wl, b_gcn, prelu_a, b_bil, outp);
}

// Round 4
// 360.313 us; speedup vs baseline: 1.8335x; 1.0186x over previous
//
#include <hip/hip_runtime.h>
#include <stdint.h>
#include <math.h>

#define SS 8
#define NBLK 8192
#define DIN 512
#define DOUT 256
#define GB 8              // graph blocks per WG
#define MT 64             // rows per WG
#define BK 32             // K chunk
#define KSTEPS 16         // DIN/BK
#define VSTR 264          // anchor bf16 LDS stride
#define EPSN 1e-12f

typedef __bf16 bf16;
typedef __bf16 bf16x8 __attribute__((ext_vector_type(8)));
typedef float  f32x4  __attribute__((ext_vector_type(4)));

typedef __attribute__((address_space(3))) uint32_t       lds_u32;
typedef __attribute__((address_space(1))) const uint32_t g_u32;

__device__ __forceinline__ void dma16(const void* g, void* l) {
    // async global->LDS, 16 B per lane; LDS dest = wave-uniform base + lane*16
    __builtin_amdgcn_global_load_lds((g_u32*)g, (lds_u32*)l, 16, 0, 0);
}

__device__ __forceinline__ bf16x8 cvt8(f32x4 lo, f32x4 hi) {
    bf16x8 r;
    r[0] = (bf16)lo[0]; r[1] = (bf16)lo[1]; r[2] = (bf16)lo[2]; r[3] = (bf16)lo[3];
    r[4] = (bf16)hi[0]; r[5] = (bf16)hi[1]; r[6] = (bf16)hi[2]; r[7] = (bf16)hi[3];
    return r;
}

// ---- prep: Wt = W_gcn^T in bf16 [n][k]; W_bil split into bf16 hi+lo ----
__global__ void prep_kernel(const float* __restrict__ W_gcn,
                            const float* __restrict__ W_bil,
                            bf16* __restrict__ Wt,
                            bf16* __restrict__ Wh,
                            bf16* __restrict__ Wl) {
    int idx = blockIdx.x * 256 + threadIdx.x;   // 196608 total
    if (idx < DIN * DOUT) {
        int k = idx >> 8, n = idx & 255;
        Wt[n * DIN + k] = (bf16)W_gcn[idx];
    } else {
        int j = idx - DIN * DOUT;               // < 65536
        float wv = W_bil[j];
        bf16 h = (bf16)wv;
        Wh[j] = h;
        Wl[j] = (bf16)(wv - (float)h);
    }
}

__global__ __launch_bounds__(256, 2) void cola_fused4(
    const float* __restrict__ pos_x, const float* __restrict__ neg_x,
    const int* __restrict__ pos_src, const int* __restrict__ pos_dst,
    const float* __restrict__ pos_w,
    const int* __restrict__ neg_src, const int* __restrict__ neg_dst,
    const float* __restrict__ neg_w,
    const bf16* __restrict__ Wt, const bf16* __restrict__ Wh,
    const bf16* __restrict__ Wl,
    const float* __restrict__ b_gcn, const float* __restrict__ prelu_a,
    const float* __restrict__ b_bil, float* __restrict__ out)
{
    __shared__ __align__(16) float bufA[2][2][MT * BK];   // [dbuf][pos/neg] fp32, 32 KB
    __shared__ __align__(16) bf16  bufB[2][DOUT * BK];    // dbuf bf16, 32 KB
    __shared__ float adjP[GB][SS][SS];                    // 2 KB
    __shared__ float adjN[GB][SS][SS];                    // 2 KB
    __shared__ float red[5 * GB];                         // ssqP|ssqA|ssqN|scoreP|scoreN

    // epilogue buffers aliased onto bufB (dead after K-loop)
    float* pool_pos = (float*)&bufB[0][0];                // 8 KB
    float* v_lds    = pool_pos + GB * DOUT;               // 8 KB
    bf16*  ahs      = (bf16*)(v_lds + GB * DOUT);         // 4.125 KB
    bf16*  als      = ahs + GB * VSTR;                    // 4.125 KB

    const int t    = threadIdx.x;
    const int wg   = blockIdx.x;
    const int w    = t >> 6;
    const int lane = t & 63;
    const int q    = lane >> 4;
    const int r15  = lane & 15;
    const int row0 = wg * MT;

    // ---- zero adjacency + reductions ----
    for (int i = t; i < GB * 64; i += 256) { ((float*)adjP)[i] = 0.f; ((float*)adjN)[i] = 0.f; }
    if (t < 5 * GB) red[t] = 0.f;
    __syncthreads();

    // ---- build weighted adjacency (edges block-contiguous, 64/block) ----
    {
        int2   sp2 = ((const int2*)pos_src)[wg * 256 + t];
        int2   dp2 = ((const int2*)pos_dst)[wg * 256 + t];
        float2 wp2 = ((const float2*)pos_w)[wg * 256 + t];
        int2   sn2 = ((const int2*)neg_src)[wg * 256 + t];
        int2   dn2 = ((const int2*)neg_dst)[wg * 256 + t];
        float2 wn2 = ((const float2*)neg_w)[wg * 256 + t];
        int gl = t >> 5;
        int base = (wg * GB + gl) * SS;
        atomicAdd(&adjP[gl][dp2.x - base][sp2.x - base], wp2.x);
        atomicAdd(&adjP[gl][dp2.y - base][sp2.y - base], wp2.y);
        atomicAdd(&adjN[gl][dn2.x - base][sn2.x - base], wn2.x);
        atomicAdd(&adjN[gl][dn2.y - base][sn2.y - base], wn2.y);
    }
    // adj visibility covered by the first K-loop barrier

    // ---- DMA lane mapping ----
    // A: chunk c covers rows c*8..c*8+7; lane: row = c*8+(lane>>3),
    //    stored k-quarter = lane&7 holds actual quarter (lane&7)^(lane>>3)  (XOR swizzle)
    const int arow_off = lane >> 3;                 // 0..7
    const int akq      = (lane & 7) ^ arow_off;     // actual global quarter to fetch
    // B: chunk c covers n-rows c*16..c*16+15; lane: n = c*16+(lane>>2), k-oct = lane&3
    const int bn_off = lane >> 2;                   // 0..15
    const int bkq    = lane & 3;

    auto issue = [&](int s, int bufi) {
        const int kbase = s * BK;
#pragma unroll
        for (int h = 0; h < 2; ++h) {
            int c = w * 2 + h;
            int row = c * 8 + arow_off;
            dma16(pos_x + (size_t)(row0 + row) * DIN + kbase + akq * 4,
                  &bufA[bufi][0][c * 256]);
            dma16(neg_x + (size_t)(row0 + row) * DIN + kbase + akq * 4,
                  &bufA[bufi][1][c * 256]);
        }
#pragma unroll
        for (int j = 0; j < 4; ++j) {
            int c = w * 4 + j;
            dma16(Wt + (size_t)(c * 16 + bn_off) * DIN + kbase + bkq * 8,
                  &bufB[bufi][c * 512]);
        }
    };

    // ================= K-loop: one barrier per step, async DMA staging ========
    f32x4 accp[4][4], accn[4][4];
#pragma unroll
    for (int mi = 0; mi < 4; ++mi)
#pragma unroll
        for (int ni = 0; ni < 4; ++ni) {
            accp[mi][ni] = (f32x4){0.f, 0.f, 0.f, 0.f};
            accn[mi][ni] = (f32x4){0.f, 0.f, 0.f, 0.f};
        }

    issue(0, 0);
    int cur = 0;
    for (int s = 0; s < KSTEPS; ++s) {
        __syncthreads();                         // drains DMA (vmcnt 0) + lgkm
        if (s + 1 < KSTEPS) issue(s + 1, cur ^ 1);

        bf16x8 afp[4], afn[4], bfv[4];
        const int q0 = (2 * q) ^ (r15 & 7);      // stored quarter holding j=0..3
        const int q1 = q0 ^ 1;                   // stored quarter holding j=4..7
#pragma unroll
        for (int mi = 0; mi < 4; ++mi) {
            int m = mi * 16 + r15;
            f32x4 lo = *(const f32x4*)&bufA[cur][0][m * BK + q0 * 4];
            f32x4 hi = *(const f32x4*)&bufA[cur][0][m * BK + q1 * 4];
            afp[mi] = cvt8(lo, hi);
            lo = *(const f32x4*)&bufA[cur][1][m * BK + q0 * 4];
            hi = *(const f32x4*)&bufA[cur][1][m * BK + q1 * 4];
            afn[mi] = cvt8(lo, hi);
        }
#pragma unroll
        for (int ni = 0; ni < 4; ++ni) {
            int n = w * 64 + ni * 16 + r15;
            bfv[ni] = *(const bf16x8*)&bufB[cur][n * BK + q * 8];
        }
#pragma unroll
        for (int mi = 0; mi < 4; ++mi)
#pragma unroll
            for (int ni = 0; ni < 4; ++ni) {
                accp[mi][ni] = __builtin_amdgcn_mfma_f32_16x16x32_bf16(
                    afp[mi], bfv[ni], accp[mi][ni], 0, 0, 0);
                accn[mi][ni] = __builtin_amdgcn_mfma_f32_16x16x32_bf16(
                    afn[mi], bfv[ni], accn[mi][ni], 0, 0, 0);
            }
        cur ^= 1;
    }
    __syncthreads();    // all bufB reads done before epilogue aliasing writes

    const float pa = *prelu_a;

    // ================= POS epilogue =================
#pragma unroll
    for (int mi = 0; mi < 4; ++mi) {
        const int gl = mi * 2 + (q >> 1);
        float part = 0.f;
#pragma unroll
        for (int ni = 0; ni < 4; ++ni) {
            float r0, r1, r2, r3, r4, r5, r6, r7;
#pragma unroll
            for (int r = 0; r < 4; ++r) {
                float own = accp[mi][ni][r];
                float oth = __shfl_xor(own, 16);
                float lo = ((q & 1) == 0) ? own : oth;
                float hi = ((q & 1) == 0) ? oth : own;
                if (r == 0) { r0 = lo; r4 = hi; }
                else if (r == 1) { r1 = lo; r5 = hi; }
                else if (r == 2) { r2 = lo; r6 = hi; }
                else            { r3 = lo; r7 = hi; }
            }
            int c = w * 64 + ni * 16 + r15;
            float bg = b_gcn[c];
            float pool = 0.f, anch = 0.f;
#pragma unroll
            for (int d = 0; d < 8; ++d) {
                const float* ar = &adjP[gl][d][0];
                float a = bg + ar[0]*r0 + ar[1]*r1 + ar[2]*r2 + ar[3]*r3
                             + ar[4]*r4 + ar[5]*r5 + ar[6]*r6 + ar[7]*r7;
                float h = (a >= 0.f) ? a : pa * a;
                if (d < 7) pool += h; else anch = h;
            }
            float pl = pool * (1.f / 7.f);
            if ((q & 1) == 0) {
                pool_pos[gl * DOUT + c] = pl;
                part += pl * pl;
            } else {
                bf16 hh = (bf16)anch;
                ahs[gl * VSTR + c] = hh;
                als[gl * VSTR + c] = (bf16)(anch - (float)hh);
                part += anch * anch;
            }
        }
        part += __shfl_xor(part, 8);
        part += __shfl_xor(part, 4);
        part += __shfl_xor(part, 2);
        part += __shfl_xor(part, 1);
        if (r15 == 0) atomicAdd((q & 1) ? &red[GB + gl] : &red[gl], part);
    }
    __syncthreads();

    // ================= v = W_bil . anchor  (3-term bf16 split MFMA) ===========
    {
        f32x4 accv[4];
#pragma unroll
        for (int ni = 0; ni < 4; ++ni) accv[ni] = (f32x4){0.f, 0.f, 0.f, 0.f};
        const int ga = (r15 & 7) * VSTR;        // rows 8..15 duplicate 0..7
#pragma unroll
        for (int ks = 0; ks < 8; ++ks) {
            bf16x8 ah_f = *(const bf16x8*)(ahs + ga + ks * 32 + q * 8);
            bf16x8 al_f = *(const bf16x8*)(als + ga + ks * 32 + q * 8);
#pragma unroll
            for (int ni = 0; ni < 4; ++ni) {
                int d = w * 64 + ni * 16 + r15;
                bf16x8 bh = *(const bf16x8*)(Wh + (size_t)d * DOUT + ks * 32 + q * 8);
                bf16x8 bl = *(const bf16x8*)(Wl + (size_t)d * DOUT + ks * 32 + q * 8);
                accv[ni] = __builtin_amdgcn_mfma_f32_16x16x32_bf16(ah_f, bh, accv[ni], 0, 0, 0);
                accv[ni] = __builtin_amdgcn_mfma_f32_16x16x32_bf16(al_f, bh, accv[ni], 0, 0, 0);
                accv[ni] = __builtin_amdgcn_mfma_f32_16x16x32_bf16(ah_f, bl, accv[ni], 0, 0, 0);
            }
        }
        float sp[4] = {0.f, 0.f, 0.f, 0.f};
        if (q < 2) {
#pragma unroll
            for (int ni = 0; ni < 4; ++ni) {
                int c = w * 64 + ni * 16 + r15;
#pragma unroll
                for (int r = 0; r < 4; ++r) {
                    int g = q * 4 + r;
                    v_lds[g * DOUT + c] = accv[ni][r];
                    sp[r] += accv[ni][r] * pool_pos[g * DOUT + c];
                }
            }
        }
#pragma unroll
        for (int r = 0; r < 4; ++r) {
            sp[r] += __shfl_xor(sp[r], 8);
            sp[r] += __shfl_xor(sp[r], 4);
            sp[r] += __shfl_xor(sp[r], 2);
            sp[r] += __shfl_xor(sp[r], 1);
        }
        if (q < 2 && r15 == 0) {
#pragma unroll
            for (int r = 0; r < 4; ++r) atomicAdd(&red[3 * GB + q * 4 + r], sp[r]);
        }
    }
    __syncthreads();

    // ================= NEG epilogue ===========================================
#pragma unroll
    for (int mi = 0; mi < 4; ++mi) {
        const int gl = mi * 2 + (q >> 1);
        float part = 0.f;
#pragma unroll
        for (int ni = 0; ni < 4; ++ni) {
            float r0, r1, r2, r3, r4, r5, r6, r7;
#pragma unroll
            for (int r = 0; r < 4; ++r) {
                float own = accn[mi][ni][r];
                float oth = __shfl_xor(own, 16);
                float lo = ((q & 1) == 0) ? own : oth;
                float hi = ((q & 1) == 0) ? oth : own;
                if (r == 0) { r0 = lo; r4 = hi; }
                else if (r == 1) { r1 = lo; r5 = hi; }
                else if (r == 2) { r2 = lo; r6 = hi; }
                else            { r3 = lo; r7 = hi; }
            }
            int c = w * 64 + ni * 16 + r15;
            float bg = b_gcn[c];
            float pool = 0.f;
#pragma unroll
            for (int d = 0; d < 7; ++d) {
                const float* ar = &adjN[gl][d][0];
                float a = bg + ar[0]*r0 + ar[1]*r1 + ar[2]*r2 + ar[3]*r3
                             + ar[4]*r4 + ar[5]*r5 + ar[6]*r6 + ar[7]*r7;
                float h = (a >= 0.f) ? a : pa * a;
                pool += h;
            }
            float pl = pool * (1.f / 7.f);
            part += ((q & 1) == 0) ? pl * v_lds[gl * DOUT + c] : pl * pl;
        }
        part += __shfl_xor(part, 8);
        part += __shfl_xor(part, 4);
        part += __shfl_xor(part, 2);
        part += __shfl_xor(part, 1);
        if (r15 == 0) atomicAdd((q & 1) ? &red[2 * GB + gl] : &red[4 * GB + gl], part);
    }
    __syncthreads();

    // ================= finalize ===============================================
    if (t < GB) {
        float np = fmaxf(sqrtf(red[t]), EPSN);
        float na = fmaxf(sqrtf(red[GB + t]), EPSN);
        float nn = fmaxf(sqrtf(red[2 * GB + t]), EPSN);
        float bb = b_bil[0];
        out[wg * GB + t]        = red[3 * GB + t] / (np * na) + bb;
        out[NBLK + wg * GB + t] = red[4 * GB + t] / (nn * na) + bb;
    }
}

extern "C" void kernel_launch(void* const* d_in, const int* in_sizes, int n_in,
                              void* d_out, int out_size, void* d_ws, size_t ws_size,
                              hipStream_t stream) {
    const float* pos_x   = (const float*)d_in[0];
    const float* neg_x   = (const float*)d_in[1];
    const int*   pos_src = (const int*)d_in[2];
    const int*   pos_dst = (const int*)d_in[3];
    const float* pos_w   = (const float*)d_in[4];
    const int*   neg_src = (const int*)d_in[5];
    const int*   neg_dst = (const int*)d_in[6];
    const float* neg_w   = (const float*)d_in[7];
    const float* W_gcn   = (const float*)d_in[8];
    const float* b_gcn   = (const float*)d_in[9];
    const float* prelu_a = (const float*)d_in[10];
    const float* W_bil   = (const float*)d_in[11];
    const float* b_bil   = (const float*)d_in[12];
    float* outp = (float*)d_out;

    bf16* Wt = (bf16*)d_ws;                 // 256 KB
    bf16* Wh = Wt + DIN * DOUT;             // 128 KB
    bf16* Wl = Wh + DOUT * DOUT;            // 128 KB

    prep_kernel<<<(DIN * DOUT + DOUT * DOUT) / 256, 256, 0, stream>>>(W_gcn, W_bil, Wt, Wh, Wl);
    cola_fused4<<<NBLK / GB, 256, 0, stream>>>(
        pos_x, neg_x, pos_src, pos_dst, pos_w, neg_src, neg_dst, neg_w,
        Wt, Wh, Wl, b_gcn, prelu_a, b_bil, outp);
}